// Round 5
// baseline (224.725 us; speedup 1.0000x reference)
//
#include <hip/hip_runtime.h>
#include <math.h>

#define D_MODEL 4096
#define N_EXP   64

typedef _Float16 half8 __attribute__((ext_vector_type(8)));
typedef float    f32x4 __attribute__((ext_vector_type(4)));

// ---------------------------------------------------------------------------
// Prep: W[64][4096] fp32 -> fragment-ordered fp16 hi/lo arrays (in d_ws).
// Ws = W*64; hi = fp16(Ws); lo = fp16((Ws-hi)*4096). Fragment order:
// element (kstep,nt,lane,j) at ((kstep*4+nt)*64+lane)*8+j, expert
// e = nt*16+(lane&15), k = kstep*32+(lane>>4)*8+j. (Verified passing in R4.)
// ---------------------------------------------------------------------------
__global__ __launch_bounds__(256)
void wprep_kernel(const float* __restrict__ W,
                  _Float16* __restrict__ whf, _Float16* __restrict__ wlf) {
    const int gid   = blockIdx.x * 256 + threadIdx.x;   // 0..32767
    const int lane  = gid & 63;
    const int ntk   = gid >> 6;
    const int nt    = ntk & 3;
    const int kstep = ntk >> 2;
    const int e  = nt * 16 + (lane & 15);
    const int k0 = kstep * 32 + (lane >> 4) * 8;

    const float* src = W + (size_t)e * D_MODEL + k0;
    float4 w0 = *(const float4*)(src);
    float4 w1 = *(const float4*)(src + 4);
    float wv[8] = {w0.x, w0.y, w0.z, w0.w, w1.x, w1.y, w1.z, w1.w};

    half8 hh, ll;
    #pragma unroll
    for (int j = 0; j < 8; ++j) {
        float ws = wv[j] * 64.0f;
        _Float16 h = (_Float16)ws;
        hh[j] = h;
        ll[j] = (_Float16)((ws - (float)h) * 4096.0f);
    }
    *(half8*)(whf + (size_t)gid * 8) = hh;
    *(half8*)(wlf + (size_t)gid * 8) = ll;
}

// ---------------------------------------------------------------------------
// Main: wave = 32 tokens (2 strips of 16) x FULL K. Block = 4 waves = 128
// tokens -> 256 blocks (1/CU). No LDS, no barriers. B demand = 256 blocks
// x 1MB = 256MB (4x less than R4 -> less L2 thrash). A-prefetch depth 2.
// ---------------------------------------------------------------------------
struct Afrag { float4 s0a, s0b, s1a, s1b; };

__device__ __forceinline__ Afrag loadA(const float* __restrict__ ax0,
                                       const float* __restrict__ ax1, int ks) {
    Afrag f;
    f.s0a = *(const float4*)(ax0 + (size_t)ks * 32);
    f.s0b = *(const float4*)(ax0 + (size_t)ks * 32 + 4);
    f.s1a = *(const float4*)(ax1 + (size_t)ks * 32);
    f.s1b = *(const float4*)(ax1 + (size_t)ks * 32 + 4);
    return f;
}

__device__ __forceinline__ void cvt_hilo(const float4 a, const float4 b,
                                         half8& hi, half8& lo) {
    float av[8] = {a.x, a.y, a.z, a.w, b.x, b.y, b.z, b.w};
    #pragma unroll
    for (int j = 0; j < 8; ++j) {
        _Float16 h = (_Float16)av[j];
        hi[j] = h;
        lo[j] = (_Float16)((av[j] - (float)h) * 4096.0f);
    }
}

__device__ __forceinline__ void kcompute(const Afrag& A,
                                         const _Float16* __restrict__ bh_base,
                                         const _Float16* __restrict__ bl_base,
                                         int ks,
                                         f32x4 hh[2][4], f32x4 cc[2][4]) {
    // B loads issued first; L2 latency hides under the A-convert VALU
    half8 bh[4], bl[4];
    const size_t boff = (size_t)(ks * 4) * 512;
    #pragma unroll
    for (int nt = 0; nt < 4; ++nt) {
        bh[nt] = *(const half8*)(bh_base + boff + nt * 512);
        bl[nt] = *(const half8*)(bl_base + boff + nt * 512);
    }
    half8 ah[2], al[2];
    cvt_hilo(A.s0a, A.s0b, ah[0], al[0]);
    cvt_hilo(A.s1a, A.s1b, ah[1], al[1]);

    // all hh, then c-pass1, then c-pass2: no back-to-back same-acc chains
    #pragma unroll
    for (int s = 0; s < 2; ++s)
        #pragma unroll
        for (int nt = 0; nt < 4; ++nt)
            hh[s][nt] = __builtin_amdgcn_mfma_f32_16x16x32_f16(ah[s], bh[nt], hh[s][nt], 0, 0, 0);
    #pragma unroll
    for (int s = 0; s < 2; ++s)
        #pragma unroll
        for (int nt = 0; nt < 4; ++nt)
            cc[s][nt] = __builtin_amdgcn_mfma_f32_16x16x32_f16(ah[s], bl[nt], cc[s][nt], 0, 0, 0);
    #pragma unroll
    for (int s = 0; s < 2; ++s)
        #pragma unroll
        for (int nt = 0; nt < 4; ++nt)
            cc[s][nt] = __builtin_amdgcn_mfma_f32_16x16x32_f16(al[s], bh[nt], cc[s][nt], 0, 0, 0);
}

__global__ __launch_bounds__(256, 1)
void router_kernel(const float* __restrict__ x,
                   const _Float16* __restrict__ whf,
                   const _Float16* __restrict__ wlf,
                   float* __restrict__ out, int ntok) {
    const int tid  = threadIdx.x;
    const int w    = tid >> 6;
    const int l    = tid & 63;
    const int tok0 = blockIdx.x * 128 + w * 32;

    const float* ax0 = x + (size_t)(tok0 + (l & 15)) * D_MODEL + (l >> 4) * 8;
    const float* ax1 = ax0 + (size_t)16 * D_MODEL;
    const _Float16* bh_base = whf + (size_t)l * 8;
    const _Float16* bl_base = wlf + (size_t)l * 8;

    f32x4 acc_hh[2][4], acc_c[2][4];
    #pragma unroll
    for (int s = 0; s < 2; ++s)
        #pragma unroll
        for (int nt = 0; nt < 4; ++nt) {
            acc_hh[s][nt] = (f32x4)0.0f;
            acc_c[s][nt]  = (f32x4)0.0f;
        }

    // A-prefetch depth 2 (>=32KB outstanding/CU, covers HBM latency)
    Afrag A0 = loadA(ax0, ax1, 0);
    Afrag A1 = loadA(ax0, ax1, 1);

    #pragma unroll 4
    for (int ks = 0; ks < 128; ++ks) {
        const int ka = (ks + 2 < 128) ? ks + 2 : 127;   // tail: harmless re-read
        Afrag An = loadA(ax0, ax1, ka);
        kcompute(A0, bh_base, bl_base, ks, acc_hh, acc_c);
        A0 = A1; A1 = An;
    }

    // logits' = (hh + c*2^-12) * 2^-6
    float* out_e = out + (size_t)2 * ntok;

    #pragma unroll
    for (int s = 0; s < 2; ++s) {
        float tt[4][4];   // [nt][q]
        #pragma unroll
        for (int nt = 0; nt < 4; ++nt) {
            f32x4 tot = (acc_hh[s][nt] + acc_c[s][nt] * (1.0f / 4096.0f)) * (1.0f / 64.0f);
            tt[nt][0] = tot.x; tt[nt][1] = tot.y; tt[nt][2] = tot.z; tt[nt][3] = tot.w;
        }
        #pragma unroll
        for (int q = 0; q < 4; ++q) {
            // C/D layout: col = lane&15 (expert sub), row = (lane>>4)*4 + q
            float v1 = -3.0e38f, v2 = -3.0e38f;
            int   i1 = 1 << 30,  i2 = 1 << 30;
            #pragma unroll
            for (int nt = 0; nt < 4; ++nt) {
                float v  = tt[nt][q];
                int   id = nt * 16 + (l & 15);
                if (v > v1 || (v == v1 && id < i1)) {
                    v2 = v1; i2 = i1; v1 = v; i1 = id;
                } else if (v > v2 || (v == v2 && id < i2)) {
                    v2 = v; i2 = id;
                }
            }
            // butterfly top-2 merge over the 16-lane group
            #pragma unroll
            for (int m = 1; m < 16; m <<= 1) {
                float ov1 = __shfl_xor(v1, m, 64);
                int   oi1 = __shfl_xor(i1, m, 64);
                float ov2 = __shfl_xor(v2, m, 64);
                int   oi2 = __shfl_xor(i2, m, 64);
                bool ofirst = (ov1 > v1) || (ov1 == v1 && oi1 < i1);
                if (ofirst) {
                    bool s2 = (ov2 > v1) || (ov2 == v1 && oi2 < i1);
                    v2 = s2 ? ov2 : v1;  i2 = s2 ? oi2 : i1;
                    v1 = ov1;            i1 = oi1;
                } else {
                    bool s2 = (ov1 > v2) || (ov1 == v2 && oi1 < i2);
                    v2 = s2 ? ov1 : v2;  i2 = s2 ? oi1 : i2;
                }
            }

            if ((l & 15) == 0) {
                const int tok = tok0 + s * 16 + (l >> 4) * 4 + q;
                float e = expf(v2 - v1);     // <= 1
                float d = 1.0f + e;
                out[2 * tok + 0] = 1.0f / d;
                out[2 * tok + 1] = e / d;
                out_e[2 * tok + 0] = (float)i1;
                out_e[2 * tok + 1] = (float)i2;
            }
        }
    }
}

extern "C" void kernel_launch(void* const* d_in, const int* in_sizes, int n_in,
                              void* d_out, int out_size, void* d_ws, size_t ws_size,
                              hipStream_t stream) {
    const float* x = (const float*)d_in[0];
    const float* W = (const float*)d_in[1];
    float* out = (float*)d_out;
    const int ntok = in_sizes[0] / D_MODEL;   // 32768

    _Float16* whf = (_Float16*)d_ws;                           // 512 KB
    _Float16* wlf = (_Float16*)d_ws + (size_t)N_EXP * D_MODEL; // 512 KB

    wprep_kernel<<<dim3(128), dim3(256), 0, stream>>>(W, whf, wlf);
    router_kernel<<<dim3(ntok / 128), dim3(256), 0, stream>>>(x, whf, wlf, out, ntok);
}

// Round 6
// 143.221 us; speedup vs baseline: 1.5691x; 1.5691x over previous
//
#include <hip/hip_runtime.h>
#include <math.h>

#define D_MODEL 4096
#define N_EXP   64

typedef _Float16 half8 __attribute__((ext_vector_type(8)));
typedef float    f32x4 __attribute__((ext_vector_type(4)));

// ---------------------------------------------------------------------------
// Prep: W[64][4096] fp32 -> fragment-ordered fp16 hi/lo arrays (in d_ws).
// Ws = W*64; hi = fp16(Ws); lo = fp16((Ws-hi)*4096). Fragment order:
// element (kstep,nt,lane,j) at ((kstep*4+nt)*64+lane)*8+j, expert
// e = nt*16+(lane&15), k = kstep*32+(lane>>4)*8+j. (Verified in R4/R5.)
// ---------------------------------------------------------------------------
__global__ __launch_bounds__(256)
void wprep_kernel(const float* __restrict__ W,
                  _Float16* __restrict__ whf, _Float16* __restrict__ wlf) {
    const int gid   = blockIdx.x * 256 + threadIdx.x;   // 0..32767
    const int lane  = gid & 63;
    const int ntk   = gid >> 6;
    const int nt    = ntk & 3;
    const int kstep = ntk >> 2;
    const int e  = nt * 16 + (lane & 15);
    const int k0 = kstep * 32 + (lane >> 4) * 8;

    const float* src = W + (size_t)e * D_MODEL + k0;
    float4 w0 = *(const float4*)(src);
    float4 w1 = *(const float4*)(src + 4);
    float wv[8] = {w0.x, w0.y, w0.z, w0.w, w1.x, w1.y, w1.z, w1.w};

    half8 hh, ll;
    #pragma unroll
    for (int j = 0; j < 8; ++j) {
        float ws = wv[j] * 64.0f;
        _Float16 h = (_Float16)ws;
        hh[j] = h;
        ll[j] = (_Float16)((ws - (float)h) * 4096.0f);
    }
    *(half8*)(whf + (size_t)gid * 8) = hh;
    *(half8*)(wlf + (size_t)gid * 8) = ll;
}

// global -> LDS direct (16B/lane, linear lane*16 dest = our fragment layout)
#define GLD16(gp, lp) __builtin_amdgcn_global_load_lds( \
    (const __attribute__((address_space(1))) unsigned int*)(const void*)(gp), \
    (__attribute__((address_space(3))) unsigned int*)(void*)(lp), 16, 0, 0)

__device__ __forceinline__ void cvt_hilo(const float4 a, const float4 b,
                                         half8& hi, half8& lo) {
    float av[8] = {a.x, a.y, a.z, a.w, b.x, b.y, b.z, b.w};
    #pragma unroll
    for (int j = 0; j < 8; ++j) {
        _Float16 h = (_Float16)av[j];
        hi[j] = h;
        lo[j] = (_Float16)((av[j] - (float)h) * 4096.0f);
    }
}

// ---------------------------------------------------------------------------
// Main: 512 threads = 8 waves x 16 tokens = 128 tokens/block, 256 blocks
// (1/CU, 8 waves/CU = 2/SIMD). B staged ONCE per block into LDS (double-
// buffered groups of 8 ksteps, 128 KiB) -> 8x cross-wave B reuse; hot loop
// reads B via conflict-free ds_read_b128. A: depth-4 named-register ring
// straight from global (each x element read exactly once). ~130 VGPR.
// ---------------------------------------------------------------------------
__global__ __launch_bounds__(512, 1)
void router_kernel(const float* __restrict__ x,
                   const _Float16* __restrict__ whf,
                   const _Float16* __restrict__ wlf,
                   float* __restrict__ out, int ntok) {
    __shared__ _Float16 sB[2][8][2][4][512];   // [buf][ksl][hi/lo][nt][lane*8] = 128 KiB

    const int tid  = threadIdx.x;
    const int w    = tid >> 6;    // wave 0..7 -> token strip & staged kstep
    const int l    = tid & 63;
    const int tok0 = blockIdx.x * 128;
    const float* ax = x + (size_t)(tok0 + w * 16 + (l & 15)) * D_MODEL + (l >> 4) * 8;

    f32x4 hh[4], cc[4];
    #pragma unroll
    for (int nt = 0; nt < 4; ++nt) { hh[nt] = (f32x4)0.0f; cc[nt] = (f32x4)0.0f; }

    // prologue: stage group 0 (wave w stages kstep ksg = w, all nt, hi+lo)
    {
        const size_t co = ((size_t)w * 4) * 512 + (size_t)l * 8;
        #pragma unroll
        for (int nt = 0; nt < 4; ++nt) {
            GLD16(whf + co + nt * 512, &sB[0][w][0][nt][0]);
            GLD16(wlf + co + nt * 512, &sB[0][w][1][nt][0]);
        }
    }
    // A-ring prologue: ks = 0..3
    float4 A0a = *(const float4*)(ax + 0 * 32), A0b = *(const float4*)(ax + 0 * 32 + 4);
    float4 A1a = *(const float4*)(ax + 1 * 32), A1b = *(const float4*)(ax + 1 * 32 + 4);
    float4 A2a = *(const float4*)(ax + 2 * 32), A2b = *(const float4*)(ax + 2 * 32 + 4);
    float4 A3a = *(const float4*)(ax + 3 * 32), A3b = *(const float4*)(ax + 3 * 32 + 4);

    __syncthreads();

    for (int g = 0; g < 16; ++g) {
        const int cur = g & 1;
        if (g < 15) {   // stage next group into the other buffer
            const int ksg = (g + 1) * 8 + w;
            const size_t co = ((size_t)ksg * 4) * 512 + (size_t)l * 8;
            #pragma unroll
            for (int nt = 0; nt < 4; ++nt) {
                GLD16(whf + co + nt * 512, &sB[cur ^ 1][w][0][nt][0]);
                GLD16(wlf + co + nt * 512, &sB[cur ^ 1][w][1][nt][0]);
            }
        }

        // 8 ksteps, fully unrolled; ring slot = ksl&3 (static)
#define STEP(KSL, SA, SB)                                                      \
        {                                                                      \
            const int ks = g * 8 + KSL;                                        \
            half8 ah, al;                                                      \
            cvt_hilo(SA, SB, ah, al);          /* consume slot */              \
            const int kp = (ks + 4 < 128) ? (ks + 4) : 127;                    \
            SA = *(const float4*)(ax + (size_t)kp * 32);      /* refill */     \
            SB = *(const float4*)(ax + (size_t)kp * 32 + 4);                   \
            half8 bh[4], bl[4];                                                \
            _Pragma("unroll")                                                  \
            for (int nt = 0; nt < 4; ++nt) {                                   \
                bh[nt] = *(const half8*)&sB[cur][KSL][0][nt][l * 8];           \
                bl[nt] = *(const half8*)&sB[cur][KSL][1][nt][l * 8];           \
            }                                                                  \
            _Pragma("unroll")                                                  \
            for (int nt = 0; nt < 4; ++nt)                                     \
                hh[nt] = __builtin_amdgcn_mfma_f32_16x16x32_f16(ah, bh[nt], hh[nt], 0, 0, 0); \
            _Pragma("unroll")                                                  \
            for (int nt = 0; nt < 4; ++nt)                                     \
                cc[nt] = __builtin_amdgcn_mfma_f32_16x16x32_f16(ah, bl[nt], cc[nt], 0, 0, 0); \
            _Pragma("unroll")                                                  \
            for (int nt = 0; nt < 4; ++nt)                                     \
                cc[nt] = __builtin_amdgcn_mfma_f32_16x16x32_f16(al, bh[nt], cc[nt], 0, 0, 0); \
        }

        STEP(0, A0a, A0b) STEP(1, A1a, A1b) STEP(2, A2a, A2b) STEP(3, A3a, A3b)
        STEP(4, A0a, A0b) STEP(5, A1a, A1b) STEP(6, A2a, A2b) STEP(7, A3a, A3b)
#undef STEP

        __syncthreads();   // staged loads drained + all reads of sB[cur] done
    }

    // logits = (hh + cc*2^-12) * 2^-6; top-2 over 16-lane butterfly
    float tt[4][4];   // [nt][q]
    #pragma unroll
    for (int nt = 0; nt < 4; ++nt) {
        f32x4 tot = (hh[nt] + cc[nt] * (1.0f / 4096.0f)) * (1.0f / 64.0f);
        tt[nt][0] = tot.x; tt[nt][1] = tot.y; tt[nt][2] = tot.z; tt[nt][3] = tot.w;
    }

    float* out_e = out + (size_t)2 * ntok;

    #pragma unroll
    for (int q = 0; q < 4; ++q) {
        // C/D layout: col = lane&15 (expert sub), row = (lane>>4)*4 + q (token)
        float v1 = -3.0e38f, v2 = -3.0e38f;
        int   i1 = 1 << 30,  i2 = 1 << 30;
        #pragma unroll
        for (int nt = 0; nt < 4; ++nt) {
            float v  = tt[nt][q];
            int   id = nt * 16 + (l & 15);
            if (v > v1 || (v == v1 && id < i1)) {
                v2 = v1; i2 = i1; v1 = v; i1 = id;
            } else if (v > v2 || (v == v2 && id < i2)) {
                v2 = v; i2 = id;
            }
        }
        #pragma unroll
        for (int m = 1; m < 16; m <<= 1) {
            float ov1 = __shfl_xor(v1, m, 64);
            int   oi1 = __shfl_xor(i1, m, 64);
            float ov2 = __shfl_xor(v2, m, 64);
            int   oi2 = __shfl_xor(i2, m, 64);
            bool ofirst = (ov1 > v1) || (ov1 == v1 && oi1 < i1);
            if (ofirst) {
                bool s2 = (ov2 > v1) || (ov2 == v1 && oi2 < i1);
                v2 = s2 ? ov2 : v1;  i2 = s2 ? oi2 : i1;
                v1 = ov1;            i1 = oi1;
            } else {
                bool s2 = (ov1 > v2) || (ov1 == v2 && oi1 < i2);
                v2 = s2 ? ov1 : v2;  i2 = s2 ? oi1 : i2;
            }
        }

        if ((l & 15) == 0) {
            const int tok = tok0 + w * 16 + (l >> 4) * 4 + q;
            float e = expf(v2 - v1);     // <= 1
            float d = 1.0f + e;
            out[2 * tok + 0] = 1.0f / d;
            out[2 * tok + 1] = e / d;
            out_e[2 * tok + 0] = (float)i1;
            out_e[2 * tok + 1] = (float)i2;
        }
    }
}

extern "C" void kernel_launch(void* const* d_in, const int* in_sizes, int n_in,
                              void* d_out, int out_size, void* d_ws, size_t ws_size,
                              hipStream_t stream) {
    const float* x = (const float*)d_in[0];
    const float* W = (const float*)d_in[1];
    float* out = (float*)d_out;
    const int ntok = in_sizes[0] / D_MODEL;   // 32768

    _Float16* whf = (_Float16*)d_ws;                           // 512 KB
    _Float16* wlf = (_Float16*)d_ws + (size_t)N_EXP * D_MODEL; // 512 KB

    wprep_kernel<<<dim3(128), dim3(256), 0, stream>>>(W, whf, wlf);
    router_kernel<<<dim3(ntok / 128), dim3(512), 0, stream>>>(x, whf, wlf, out, ntok);
}

// Round 7
// 129.502 us; speedup vs baseline: 1.7353x; 1.1059x over previous
//
#include <hip/hip_runtime.h>
#include <math.h>

#define D_MODEL 4096
#define N_EXP   64

typedef _Float16 half8 __attribute__((ext_vector_type(8)));
typedef float    f32x4 __attribute__((ext_vector_type(4)));

// ---------------------------------------------------------------------------
// Prep: W[64][4096] fp32 -> fragment-ordered fp16 hi/lo arrays (in d_ws).
// Ws = W*64; hi = fp16(Ws); lo = fp16((Ws-hi)*4096). Fragment order:
// element (kstep,nt,lane,j) at ((kstep*4+nt)*64+lane)*8+j, expert
// e = nt*16+(lane&15), k = kstep*32+(lane>>4)*8+j. (Verified R4-R6.)
// ---------------------------------------------------------------------------
__global__ __launch_bounds__(256)
void wprep_kernel(const float* __restrict__ W,
                  _Float16* __restrict__ whf, _Float16* __restrict__ wlf) {
    const int gid   = blockIdx.x * 256 + threadIdx.x;   // 0..32767
    const int lane  = gid & 63;
    const int ntk   = gid >> 6;
    const int nt    = ntk & 3;
    const int kstep = ntk >> 2;
    const int e  = nt * 16 + (lane & 15);
    const int k0 = kstep * 32 + (lane >> 4) * 8;

    const float* src = W + (size_t)e * D_MODEL + k0;
    float4 w0 = *(const float4*)(src);
    float4 w1 = *(const float4*)(src + 4);
    float wv[8] = {w0.x, w0.y, w0.z, w0.w, w1.x, w1.y, w1.z, w1.w};

    half8 hh, ll;
    #pragma unroll
    for (int j = 0; j < 8; ++j) {
        float ws = wv[j] * 64.0f;
        _Float16 h = (_Float16)ws;
        hh[j] = h;
        ll[j] = (_Float16)((ws - (float)h) * 4096.0f);
    }
    *(half8*)(whf + (size_t)gid * 8) = hh;
    *(half8*)(wlf + (size_t)gid * 8) = ll;
}

// global -> LDS direct (16B/lane, linear lane*16 dest = our fragment layout)
#define GLD16(gp, lp) __builtin_amdgcn_global_load_lds( \
    (const __attribute__((address_space(1))) unsigned int*)(const void*)(gp), \
    (__attribute__((address_space(3))) unsigned int*)(void*)(lp), 16, 0, 0)

__device__ __forceinline__ void cvt_hilo(const float4 a, const float4 b,
                                         half8& hi, half8& lo) {
    float av[8] = {a.x, a.y, a.z, a.w, b.x, b.y, b.z, b.w};
    #pragma unroll
    for (int j = 0; j < 8; ++j) {
        _Float16 h = (_Float16)av[j];
        hi[j] = h;
        lo[j] = (_Float16)((av[j] - (float)h) * 4096.0f);
    }
}

// ---------------------------------------------------------------------------
// Main: 256 threads = 4 waves x 16 tokens = 64 tokens/block, 512 blocks
// (2/CU -> barrier drains in one block covered by the other). B double-
// buffered in LDS, groups of 4 ksteps (64 KiB). A: depth-8 named-register
// ring; refills issue at group START (so at the barrier all loads are >=1
// group old -> cheap vmcnt drain).
// ---------------------------------------------------------------------------
__global__ __launch_bounds__(256, 2)
void router_kernel(const float* __restrict__ x,
                   const _Float16* __restrict__ whf,
                   const _Float16* __restrict__ wlf,
                   float* __restrict__ out, int ntok) {
    __shared__ _Float16 sB[2][4][2][4][512];   // [buf][ksl][hi/lo][nt][lane*8] = 64 KiB

    const int tid  = threadIdx.x;
    const int w    = tid >> 6;    // wave 0..3 -> token strip & staged ksl
    const int l    = tid & 63;
    const int tok0 = blockIdx.x * 64;
    const float* ax = x + (size_t)(tok0 + w * 16 + (l & 15)) * D_MODEL + (l >> 4) * 8;

    f32x4 hh[4], cc[4];
    #pragma unroll
    for (int nt = 0; nt < 4; ++nt) { hh[nt] = (f32x4)0.0f; cc[nt] = (f32x4)0.0f; }

    // prologue: stage B group 0 into buf0 (wave w stages ksl=w)
    {
        const size_t co = (size_t)w * 4 * 512 + (size_t)l * 8;
        #pragma unroll
        for (int nt = 0; nt < 4; ++nt) {
            GLD16(whf + co + nt * 512, &sB[0][w][0][nt][0]);
            GLD16(wlf + co + nt * 512, &sB[0][w][1][nt][0]);
        }
    }
    // A-ring prologue: half0 = ks0-3, half1 = ks4-7
    float4 P0a = *(const float4*)(ax + 0 * 32), P0b = *(const float4*)(ax + 0 * 32 + 4);
    float4 P1a = *(const float4*)(ax + 1 * 32), P1b = *(const float4*)(ax + 1 * 32 + 4);
    float4 P2a = *(const float4*)(ax + 2 * 32), P2b = *(const float4*)(ax + 2 * 32 + 4);
    float4 P3a = *(const float4*)(ax + 3 * 32), P3b = *(const float4*)(ax + 3 * 32 + 4);
    float4 P4a = *(const float4*)(ax + 4 * 32), P4b = *(const float4*)(ax + 4 * 32 + 4);
    float4 P5a = *(const float4*)(ax + 5 * 32), P5b = *(const float4*)(ax + 5 * 32 + 4);
    float4 P6a = *(const float4*)(ax + 6 * 32), P6b = *(const float4*)(ax + 6 * 32 + 4);
    float4 P7a = *(const float4*)(ax + 7 * 32), P7b = *(const float4*)(ax + 7 * 32 + 4);

    __syncthreads();

#define STEP(KSL, SA, SB, CUR)                                                 \
    {                                                                          \
        half8 ah, al;                                                          \
        cvt_hilo(SA, SB, ah, al);                                              \
        half8 bh[4], bl[4];                                                    \
        _Pragma("unroll")                                                      \
        for (int nt = 0; nt < 4; ++nt) {                                       \
            bh[nt] = *(const half8*)&sB[CUR][KSL][0][nt][l * 8];               \
            bl[nt] = *(const half8*)&sB[CUR][KSL][1][nt][l * 8];               \
        }                                                                      \
        _Pragma("unroll")                                                      \
        for (int nt = 0; nt < 4; ++nt)                                         \
            hh[nt] = __builtin_amdgcn_mfma_f32_16x16x32_f16(ah, bh[nt], hh[nt], 0, 0, 0); \
        _Pragma("unroll")                                                      \
        for (int nt = 0; nt < 4; ++nt)                                         \
            cc[nt] = __builtin_amdgcn_mfma_f32_16x16x32_f16(ah, bl[nt], cc[nt], 0, 0, 0); \
        _Pragma("unroll")                                                      \
        for (int nt = 0; nt < 4; ++nt)                                         \
            cc[nt] = __builtin_amdgcn_mfma_f32_16x16x32_f16(al, bh[nt], cc[nt], 0, 0, 0); \
    }

    // GROUP(g): consume buf CUR = g&1 (A-half CUR); at start, refill the half
    // consumed in group g-1 with group g+1's A data, and stage group g+1's B.
#define GROUP(G, CUR, C0a,C0b,C1a,C1b,C2a,C2b,C3a,C3b,                         \
                      O0a,O0b,O1a,O1b,O2a,O2b,O3a,O3b)                         \
    {                                                                          \
        if ((G) >= 1 && (G) <= 30) {                                           \
            const size_t kb = (size_t)((G) + 1) * 4 * 32;                      \
            O0a = *(const float4*)(ax + kb + 0 * 32);                          \
            O0b = *(const float4*)(ax + kb + 0 * 32 + 4);                      \
            O1a = *(const float4*)(ax + kb + 1 * 32);                          \
            O1b = *(const float4*)(ax + kb + 1 * 32 + 4);                      \
            O2a = *(const float4*)(ax + kb + 2 * 32);                          \
            O2b = *(const float4*)(ax + kb + 2 * 32 + 4);                      \
            O3a = *(const float4*)(ax + kb + 3 * 32);                          \
            O3b = *(const float4*)(ax + kb + 3 * 32 + 4);                      \
        }                                                                      \
        if ((G) < 31) {                                                        \
            const int ksg = ((G) + 1) * 4 + w;                                 \
            const size_t co = (size_t)ksg * 4 * 512 + (size_t)l * 8;           \
            _Pragma("unroll")                                                  \
            for (int nt = 0; nt < 4; ++nt) {                                   \
                GLD16(whf + co + nt * 512, &sB[(CUR) ^ 1][w][0][nt][0]);       \
                GLD16(wlf + co + nt * 512, &sB[(CUR) ^ 1][w][1][nt][0]);       \
            }                                                                  \
        }                                                                      \
        STEP(0, C0a, C0b, CUR)                                                 \
        STEP(1, C1a, C1b, CUR)                                                 \
        STEP(2, C2a, C2b, CUR)                                                 \
        STEP(3, C3a, C3b, CUR)                                                 \
        __syncthreads();                                                       \
    }

    for (int gg = 0; gg < 16; ++gg) {
        const int g0 = gg * 2;
        GROUP(g0,     0, P0a,P0b,P1a,P1b,P2a,P2b,P3a,P3b,
                         P4a,P4b,P5a,P5b,P6a,P6b,P7a,P7b)
        GROUP(g0 + 1, 1, P4a,P4b,P5a,P5b,P6a,P6b,P7a,P7b,
                         P0a,P0b,P1a,P1b,P2a,P2b,P3a,P3b)
    }
#undef GROUP
#undef STEP

    // logits = (hh + cc*2^-12) * 2^-6; top-2 over 16-lane butterfly
    float tt[4][4];   // [nt][q]
    #pragma unroll
    for (int nt = 0; nt < 4; ++nt) {
        f32x4 tot = (hh[nt] + cc[nt] * (1.0f / 4096.0f)) * (1.0f / 64.0f);
        tt[nt][0] = tot.x; tt[nt][1] = tot.y; tt[nt][2] = tot.z; tt[nt][3] = tot.w;
    }

    float* out_e = out + (size_t)2 * ntok;

    #pragma unroll
    for (int q = 0; q < 4; ++q) {
        // C/D layout: col = lane&15 (expert sub), row = (lane>>4)*4 + q (token)
        float v1 = -3.0e38f, v2 = -3.0e38f;
        int   i1 = 1 << 30,  i2 = 1 << 30;
        #pragma unroll
        for (int nt = 0; nt < 4; ++nt) {
            float v  = tt[nt][q];
            int   id = nt * 16 + (l & 15);
            if (v > v1 || (v == v1 && id < i1)) {
                v2 = v1; i2 = i1; v1 = v; i1 = id;
            } else if (v > v2 || (v == v2 && id < i2)) {
                v2 = v; i2 = id;
            }
        }
        #pragma unroll
        for (int m = 1; m < 16; m <<= 1) {
            float ov1 = __shfl_xor(v1, m, 64);
            int   oi1 = __shfl_xor(i1, m, 64);
            float ov2 = __shfl_xor(v2, m, 64);
            int   oi2 = __shfl_xor(i2, m, 64);
            bool ofirst = (ov1 > v1) || (ov1 == v1 && oi1 < i1);
            if (ofirst) {
                bool s2 = (ov2 > v1) || (ov2 == v1 && oi2 < i1);
                v2 = s2 ? ov2 : v1;  i2 = s2 ? oi2 : i1;
                v1 = ov1;            i1 = oi1;
            } else {
                bool s2 = (ov1 > v2) || (ov1 == v2 && oi1 < i2);
                v2 = s2 ? ov1 : v2;  i2 = s2 ? oi1 : i2;
            }
        }

        if ((l & 15) == 0) {
            const int tok = tok0 + w * 16 + (l >> 4) * 4 + q;
            float e = expf(v2 - v1);     // <= 1
            float d = 1.0f + e;
            out[2 * tok + 0] = 1.0f / d;
            out[2 * tok + 1] = e / d;
            out_e[2 * tok + 0] = (float)i1;
            out_e[2 * tok + 1] = (float)i2;
        }
    }
}

extern "C" void kernel_launch(void* const* d_in, const int* in_sizes, int n_in,
                              void* d_out, int out_size, void* d_ws, size_t ws_size,
                              hipStream_t stream) {
    const float* x = (const float*)d_in[0];
    const float* W = (const float*)d_in[1];
    float* out = (float*)d_out;
    const int ntok = in_sizes[0] / D_MODEL;   // 32768

    _Float16* whf = (_Float16*)d_ws;                           // 512 KB
    _Float16* wlf = (_Float16*)d_ws + (size_t)N_EXP * D_MODEL; // 512 KB

    wprep_kernel<<<dim3(128), dim3(256), 0, stream>>>(W, whf, wlf);
    router_kernel<<<dim3(ntok / 64), dim3(256), 0, stream>>>(x, whf, wlf, out, ntok);
}